// Round 4
// baseline (365.218 us; speedup 1.0000x reference)
//
#include <hip/hip_runtime.h>

// Problem constants (fixed by the reference)
constexpr int N_NODES = 50000;
constexpr int E_EDGES = 400000;
constexpr int IN_DIM  = 128;
constexpr int HD      = 256;   // H*D
constexpr int H_HEADS = 8;
constexpr int D_HEAD  = 32;
constexpr int M_FEAT  = 8;
constexpr int K_NODES = N_NODES / H_HEADS;   // 6250 nodes need Phi
constexpr int CAP     = 48;    // bucket capacity; deg ~ Poisson(8), P(>=48) ~ 1e-23

typedef __attribute__((ext_vector_type(8))) short bf16x8;
typedef __attribute__((ext_vector_type(4))) float f32x4;

__device__ inline short to_bf16(float f) {
    unsigned u = __builtin_bit_cast(unsigned, f);
    u += 0x7FFFu + ((u >> 16) & 1u);   // RNE; inputs are finite Gaussians
    return (short)(u >> 16);
}

// ---------------------------------------------------------------------------
// Prep kernel.
//   blocks [0,32):    Wqrf[d][c=h*8+m] = sum_dd Wq[d][h*32+dd] * RFq[dd][m]
//   blocks [32,64):   Wkrf[d][c=j*8+m] = sum_dd Wk[d][j*32+dd] * RF[dd][m]
//   blocks [64,192):  WvT[n][d] = bf16(Wv[d][n])   (k-contiguous B layout)
// ---------------------------------------------------------------------------
__global__ __launch_bounds__(256) void prep_kernel(
    const float* __restrict__ Wq, const float* __restrict__ Wk,
    const float* __restrict__ Wv, const float* __restrict__ RF,
    const float* __restrict__ RFq,
    float* __restrict__ Wqrf, float* __restrict__ Wkrf,
    unsigned short* __restrict__ WvT)
{
    const int b = blockIdx.x;
    const int t = threadIdx.x;
    if (b < 64) {
        const bool isQ = (b < 32);
        const int idx = (isQ ? b : b - 32) * 256 + t;   // 0..8191
        const int d = idx >> 6;
        const int c = idx & 63;
        const int hj = c >> 3, m = c & 7;
        const float* W  = isQ ? Wq : Wk;
        const float* R  = isQ ? RFq : RF;
        float acc = 0.f;
        #pragma unroll
        for (int dd = 0; dd < D_HEAD; ++dd)
            acc = fmaf(W[d * HD + hj * D_HEAD + dd], R[dd * M_FEAT + m], acc);
        (isQ ? Wqrf : Wkrf)[idx] = acc;
    } else {
        const int idx = (b - 64) * 256 + t;             // 0..32767
        const int n = idx >> 7;
        const int d = idx & 127;
        WvT[idx] = (unsigned short)to_bf16(Wv[d * HD + n]);
    }
}

// ---------------------------------------------------------------------------
// V kernel: V[50000,256] = x @ Wv via bf16 MFMA 16x16x32 (fp32 accumulate).
// One wave per 16 rows. A-frags converted in-register from fp32 x.
// B-frags read from L2-resident WvT (64 KB shared by all waves).
// Fragment maps (m89/m120-verified): A[m=lane&15][k=quad*8+j],
// B[k=quad*8+j][n=lane&15], C col=lane&15 row=quad*4+reg.
// ---------------------------------------------------------------------------
__global__ __launch_bounds__(256) void v_kernel(
    const float* __restrict__ x, const unsigned short* __restrict__ WvT,
    float* __restrict__ V)
{
    const int wave = blockIdx.x * 4 + (threadIdx.x >> 6);
    if (wave * 16 >= N_NODES) return;
    const int lane = threadIdx.x & 63;
    const int m    = lane & 15;
    const int quad = lane >> 4;
    const int r0   = wave * 16;

    // A fragments for all 4 k-steps (K=128)
    bf16x8 A[4];
    const float* xrow = x + (size_t)(r0 + m) * IN_DIM;
    #pragma unroll
    for (int t = 0; t < 4; ++t) {
        const float4 a = *(const float4*)(xrow + t * 32 + quad * 8);
        const float4 b = *(const float4*)(xrow + t * 32 + quad * 8 + 4);
        bf16x8 f;
        f[0] = to_bf16(a.x); f[1] = to_bf16(a.y);
        f[2] = to_bf16(a.z); f[3] = to_bf16(a.w);
        f[4] = to_bf16(b.x); f[5] = to_bf16(b.y);
        f[6] = to_bf16(b.z); f[7] = to_bf16(b.w);
        A[t] = f;
    }

    const unsigned short* bp = WvT + (size_t)m * IN_DIM + quad * 8;
    #pragma unroll
    for (int ct = 0; ct < 16; ++ct) {
        f32x4 acc = {0.f, 0.f, 0.f, 0.f};
        const unsigned short* bc = bp + (size_t)ct * 16 * IN_DIM;
        #pragma unroll
        for (int t = 0; t < 4; ++t) {
            bf16x8 B = *(const bf16x8*)(bc + t * 32);
            acc = __builtin_amdgcn_mfma_f32_16x16x32_bf16(A[t], B, acc, 0, 0, 0);
        }
        #pragma unroll
        for (int r = 0; r < 4; ++r)
            V[(size_t)(r0 + quad * 4 + r) * HD + ct * 16 + m] = acc[r];
    }
}

// ---------------------------------------------------------------------------
// S kernel: exact-fp32 random-feature path.
//   Sq[n,h]  = sum_m cos+sin( x[n] . Wqrf[:, h*8+m] )
//   Phi[n*64 + j*8+m] = cos+sin( x[n] . Wkrf[:, j*8+m] )   for n < 6250
// One wave per 8 nodes; lane = column c (64 cols). x rows read with
// wave-uniform addresses -> scalar (SMEM) loads, keeping VALU for fma.
// ---------------------------------------------------------------------------
__global__ __launch_bounds__(256) void s_kernel(
    const float* __restrict__ x,
    const float* __restrict__ Wqrf, const float* __restrict__ Wkrf,
    float* __restrict__ Sq, float* __restrict__ Phi)
{
    const int g = __builtin_amdgcn_readfirstlane(blockIdx.x * 4 + (threadIdx.x >> 6));
    const int n0 = g * 8;
    if (n0 >= N_NODES) return;
    const int c = threadIdx.x & 63;

    float accq[8];
    #pragma unroll
    for (int i = 0; i < 8; ++i) accq[i] = 0.f;

    for (int d4 = 0; d4 < IN_DIM / 4; ++d4) {
        float4 xs[8];
        #pragma unroll
        for (int i = 0; i < 8; ++i)
            xs[i] = *(const float4*)&x[(size_t)(n0 + i) * IN_DIM + d4 * 4];
        #pragma unroll
        for (int dd = 0; dd < 4; ++dd) {
            const float w = Wqrf[(d4 * 4 + dd) * 64 + c];
            #pragma unroll
            for (int i = 0; i < 8; ++i) {
                const float xv = (dd == 0) ? xs[i].x : (dd == 1) ? xs[i].y
                               : (dd == 2) ? xs[i].z : xs[i].w;
                accq[i] = fmaf(xv, w, accq[i]);
            }
        }
    }
    #pragma unroll
    for (int i = 0; i < 8; ++i) {
        float val = __cosf(accq[i]) + __sinf(accq[i]);
        val += __shfl_xor(val, 1);
        val += __shfl_xor(val, 2);
        val += __shfl_xor(val, 4);
        if ((c & 7) == 0) Sq[(n0 + i) * H_HEADS + (c >> 3)] = val;
    }

    if (n0 < K_NODES) {   // wave-uniform branch
        float acck[8];
        #pragma unroll
        for (int i = 0; i < 8; ++i) acck[i] = 0.f;
        for (int d4 = 0; d4 < IN_DIM / 4; ++d4) {
            float4 xs[8];
            #pragma unroll
            for (int i = 0; i < 8; ++i)
                xs[i] = *(const float4*)&x[(size_t)(n0 + i) * IN_DIM + d4 * 4];
            #pragma unroll
            for (int dd = 0; dd < 4; ++dd) {
                const float w = Wkrf[(d4 * 4 + dd) * 64 + c];
                #pragma unroll
                for (int i = 0; i < 8; ++i) {
                    const float xv = (dd == 0) ? xs[i].x : (dd == 1) ? xs[i].y
                                   : (dd == 2) ? xs[i].z : xs[i].w;
                    acck[i] = fmaf(xv, w, acck[i]);
                }
            }
        }
        #pragma unroll
        for (int i = 0; i < 8; ++i)
            if (n0 + i < K_NODES)
                Phi[(size_t)(n0 + i) * 64 + c] = __cosf(acck[i]) + __sinf(acck[i]);
    }
}

// ---------------------------------------------------------------------------
// Bucket edges by src (store dst) and by dst (store src|sign). 2 atomics/edge.
// ---------------------------------------------------------------------------
__global__ __launch_bounds__(256) void bucket_kernel(
    const int* __restrict__ src, const int* __restrict__ dst,
    const int* __restrict__ sign,
    int* __restrict__ srcCnt, int* __restrict__ srcBucket,
    int* __restrict__ dstCnt, unsigned* __restrict__ dstBucket)
{
    const int e = blockIdx.x * 256 + threadIdx.x;
    if (e >= E_EDGES) return;
    const int s = src[e];
    const int d = dst[e];
    const unsigned pos = (sign[e] == 1) ? 0x80000000u : 0u;

    const int ss = atomicAdd(&srcCnt[s], 1);
    if (ss < CAP) srcBucket[s * CAP + ss] = d;
    const int ds = atomicAdd(&dstCnt[d], 1);
    if (ds < CAP) dstBucket[d * CAP + ds] = (unsigned)s | pos;
}

// ---------------------------------------------------------------------------
// Gather-build pk_pos/pk_neg [N,8] and cnt_pos/cnt_neg [N]; thread per (dst,h).
// Phi flat layout: Phi[i*8 + m] for flat row i = n*8+j  (== Phi[n*64+j*8+m]).
// ---------------------------------------------------------------------------
__global__ __launch_bounds__(256) void pk_kernel(
    const int* __restrict__ dstCnt, const unsigned* __restrict__ dstBucket,
    const float* __restrict__ Phi,
    float* __restrict__ pk_pos, float* __restrict__ pk_neg,
    float* __restrict__ cnt_pos, float* __restrict__ cnt_neg)
{
    const int t = blockIdx.x * 256 + threadIdx.x;
    if (t >= N_NODES * H_HEADS) return;
    const int d = t >> 3;
    const int h = t & 7;
    int deg = dstCnt[d];
    if (deg > CAP) deg = CAP;

    float accp = 0.f, accn = 0.f;
    int cp = 0, cn = 0;
    for (int i = 0; i < deg; ++i) {
        const unsigned entry = dstBucket[d * CAP + i];
        const int s = (int)(entry & 0x7FFFFFFFu);
        const float phi = Phi[s * H_HEADS + h];
        if (entry & 0x80000000u) { accp += phi; ++cp; }
        else                     { accn += phi; ++cn; }
    }
    pk_pos[t] = accp;
    pk_neg[t] = accn;
    if (h == 0) {
        cnt_pos[d] = (float)cp;
        cnt_neg[d] = (float)cn;
    }
}

// ---------------------------------------------------------------------------
// Gather-accumulate. One wave per src node (round-2 structure).
// ---------------------------------------------------------------------------
__global__ __launch_bounds__(256) void accum_kernel(
    const int* __restrict__ srcCnt, const int* __restrict__ srcBucket,
    const float* __restrict__ Sq,
    const float* __restrict__ pk_pos, const float* __restrict__ pk_neg,
    const float* __restrict__ cnt_pos, const float* __restrict__ cnt_neg,
    const float* __restrict__ V, float* __restrict__ out)
{
    const int s = blockIdx.x * 4 + (threadIdx.x >> 6);
    const int lane = threadIdx.x & 63;
    const int j = lane >> 3;       // edge slot within batch
    const int h = lane & 7;        // head for attn compute
    const int myhead = lane >> 3;  // head of my output columns (c=4*lane)

    int deg = srcCnt[s];
    if (deg > CAP) deg = CAP;
    const float sq = Sq[s * H_HEADS + h];

    float4 acc = make_float4(0.f, 0.f, 0.f, 0.f);
    const float4* __restrict__ V4 = (const float4*)V;

    for (int base = 0; base < deg; base += 8) {
        const int idx = base + j;
        const int dj = (idx < deg) ? srcBucket[s * CAP + idx] : 0;

        const float dp = fmaxf(cnt_pos[dj], 1.0f);
        const float dn = fmaxf(cnt_neg[dj], 1.0f);
        float np = sq * pk_pos[dj * H_HEADS + h] / dp;
        float nn = sq * pk_neg[dj * H_HEADS + h] / dn;

        float mp = np, mn = nn;
        mp = fmaxf(mp, __shfl_xor(mp, 1)); mn = fmaxf(mn, __shfl_xor(mn, 1));
        mp = fmaxf(mp, __shfl_xor(mp, 2)); mn = fmaxf(mn, __shfl_xor(mn, 2));
        mp = fmaxf(mp, __shfl_xor(mp, 4)); mn = fmaxf(mn, __shfl_xor(mn, 4));
        float ep = __expf(np - mp), en = __expf(nn - mn);
        float sp = ep, sn = en;
        sp += __shfl_xor(sp, 1); sn += __shfl_xor(sn, 1);
        sp += __shfl_xor(sp, 2); sn += __shfl_xor(sn, 2);
        sp += __shfl_xor(sp, 4); sn += __shfl_xor(sn, 4);
        const float a = ep / sp - en / sn;

        int nb = deg - base;
        if (nb > 8) nb = 8;
        for (int jj = 0; jj < nb; ++jj) {
            const int   dd = __shfl(dj, jj * 8);
            const float av = __shfl(a,  jj * 8 + myhead);
            const float4 vv = V4[dd * 64 + lane];
            acc.x = fmaf(vv.x, av, acc.x);
            acc.y = fmaf(vv.y, av, acc.y);
            acc.z = fmaf(vv.z, av, acc.z);
            acc.w = fmaf(vv.w, av, acc.w);
        }
    }
    ((float4*)out)[s * 64 + lane] = acc;   // every node written -> no memset
}

extern "C" void kernel_launch(void* const* d_in, const int* in_sizes, int n_in,
                              void* d_out, int out_size, void* d_ws, size_t ws_size,
                              hipStream_t stream) {
    const float* x   = (const float*)d_in[0];
    const float* Wq  = (const float*)d_in[1];
    const float* Wk  = (const float*)d_in[2];
    const float* Wv  = (const float*)d_in[3];
    const float* RF  = (const float*)d_in[4];
    const float* RFq = (const float*)d_in[5];
    const int* eidx  = (const int*)d_in[6];
    const int* esign = (const int*)d_in[7];
    const int* src = eidx;            // edge_index[0, :]
    const int* dst = eidx + E_EDGES;  // edge_index[1, :]
    float* out = (float*)d_out;

    // Workspace layout: V | Sq | Phi | pk_pos | pk_neg | cnt_pos | cnt_neg |
    //                   srcCnt | dstCnt | srcBucket | dstBucket | Wqrf | Wkrf | WvT
    float* ws      = (float*)d_ws;
    float* V       = ws;                                  // N*256
    float* Sq      = V + (size_t)N_NODES * HD;            // N*8
    float* Phi     = Sq + (size_t)N_NODES * H_HEADS;      // 6250*64 = 400000
    float* pk_pos  = Phi + (size_t)N_NODES * M_FEAT;      // N*8
    float* pk_neg  = pk_pos + (size_t)N_NODES * H_HEADS;  // N*8
    float* cnt_pos = pk_neg + (size_t)N_NODES * H_HEADS;  // N
    float* cnt_neg = cnt_pos + N_NODES;                   // N
    int* srcCnt    = (int*)(cnt_neg + N_NODES);           // N
    int* dstCnt    = srcCnt + N_NODES;                    // N
    int* srcBucket = dstCnt + N_NODES;                    // N*CAP
    unsigned* dstBucket = (unsigned*)(srcBucket + (size_t)N_NODES * CAP); // N*CAP
    float* Wqrf    = (float*)(dstBucket + (size_t)N_NODES * CAP);  // 128*64
    float* Wkrf    = Wqrf + IN_DIM * 64;                           // 128*64
    unsigned short* WvT = (unsigned short*)(Wkrf + IN_DIM * 64);   // 256*128 bf16

    // Zero only the bucket counters (contiguous 2*N ints).
    hipMemsetAsync(srcCnt, 0, sizeof(int) * (size_t)N_NODES * 2, stream);

    prep_kernel<<<192, 256, 0, stream>>>(Wq, Wk, Wv, RF, RFq, Wqrf, Wkrf, WvT);
    bucket_kernel<<<(E_EDGES + 255) / 256, 256, 0, stream>>>(
        src, dst, esign, srcCnt, srcBucket, dstCnt, dstBucket);
    v_kernel<<<(N_NODES / 16 + 3) / 4, 256, 0, stream>>>(x, WvT, V);
    s_kernel<<<(N_NODES / 8 + 3) / 4, 256, 0, stream>>>(x, Wqrf, Wkrf, Sq, Phi);
    pk_kernel<<<(N_NODES * H_HEADS + 255) / 256, 256, 0, stream>>>(
        dstCnt, dstBucket, Phi, pk_pos, pk_neg, cnt_pos, cnt_neg);
    accum_kernel<<<N_NODES / 4, 256, 0, stream>>>(
        srcCnt, srcBucket, Sq, pk_pos, pk_neg, cnt_pos, cnt_neg, V, out);
}

// Round 5
// 277.653 us; speedup vs baseline: 1.3154x; 1.3154x over previous
//
#include <hip/hip_runtime.h>

// Problem constants (fixed by the reference)
constexpr int N_NODES = 50000;
constexpr int E_EDGES = 400000;
constexpr int IN_DIM  = 128;
constexpr int HD      = 256;   // H*D
constexpr int H_HEADS = 8;
constexpr int D_HEAD  = 32;
constexpr int M_FEAT  = 8;
constexpr int K_NODES = N_NODES / H_HEADS;   // 6250 nodes need Phi
constexpr int CAP     = 48;    // bucket capacity; deg ~ Poisson(8), P(>=48) ~ 1e-23

typedef __attribute__((ext_vector_type(8))) short bf16x8;
typedef __attribute__((ext_vector_type(4))) float f32x4;

__device__ inline short to_bf16(float f) {
    unsigned u = __builtin_bit_cast(unsigned, f);
    u += 0x7FFFu + ((u >> 16) & 1u);   // RNE; inputs are finite
    return (short)(u >> 16);
}
__device__ inline float bf16f(short h) {
    return __builtin_bit_cast(float, (unsigned)(unsigned short)h << 16);
}

// ---------------------------------------------------------------------------
// Prep kernel.
//   blocks [0,32):   Wqrf[d][c=h*8+m] = sum_dd Wq[d][h*32+dd]*RFq[dd][m],
//                    stored split-bf16 transposed: WqTh/WqTl[c*128+d]
//   blocks [32,64):  same for Wk x RF -> WkTh/WkTl
//   blocks [64,192): WvT[n*128+d] = bf16(Wv[d][n])   (col-major B layout)
// ---------------------------------------------------------------------------
__global__ __launch_bounds__(256) void prep_kernel(
    const float* __restrict__ Wq, const float* __restrict__ Wk,
    const float* __restrict__ Wv, const float* __restrict__ RF,
    const float* __restrict__ RFq,
    unsigned short* __restrict__ WqTh, unsigned short* __restrict__ WqTl,
    unsigned short* __restrict__ WkTh, unsigned short* __restrict__ WkTl,
    unsigned short* __restrict__ WvT)
{
    const int b = blockIdx.x;
    const int t = threadIdx.x;
    if (b < 64) {
        const bool isQ = (b < 32);
        const int idx = (isQ ? b : b - 32) * 256 + t;   // 0..8191
        const int d = idx >> 6;
        const int c = idx & 63;
        const int hj = c >> 3, m = c & 7;
        const float* W = isQ ? Wq : Wk;
        const float* R = isQ ? RFq : RF;
        float acc = 0.f;
        #pragma unroll
        for (int dd = 0; dd < D_HEAD; ++dd)
            acc = fmaf(W[d * HD + hj * D_HEAD + dd], R[dd * M_FEAT + m], acc);
        const short h = to_bf16(acc);
        const short l = to_bf16(acc - bf16f(h));
        (isQ ? WqTh : WkTh)[c * IN_DIM + d] = (unsigned short)h;
        (isQ ? WqTl : WkTl)[c * IN_DIM + d] = (unsigned short)l;
    } else {
        const int idx = (b - 64) * 256 + t;             // 0..32767
        const int n = idx >> 7;
        const int d = idx & 127;
        WvT[idx] = (unsigned short)to_bf16(Wv[d * HD + n]);
    }
}

// ---------------------------------------------------------------------------
// Fused transform kernel (one x pass). One wave per 16 rows.
//   V[r,0:256]  = x @ Wv             (single bf16 MFMA, fp32 acc)
//   Sq[r,h]     = sum_m cos+sin(x @ Wqrf)   (bf16-PAIR MFMA: Ah*Bh+Al*Bh+Ah*Bl)
//   Phi[r,0:64] = cos+sin(x @ Wkrf)  for r < 6250   (pair MFMA)
// Fragment maps (verified in round-4 v_kernel): A[m=lane&15][k=quad*8+j],
// B[k=quad*8+j][n=lane&15] (col-major, k-contig), C col=lane&15 row=quad*4+r.
// ---------------------------------------------------------------------------
__global__ __launch_bounds__(256) void xform_kernel(
    const float* __restrict__ x, const unsigned short* __restrict__ WvT,
    const unsigned short* __restrict__ WqTh, const unsigned short* __restrict__ WqTl,
    const unsigned short* __restrict__ WkTh, const unsigned short* __restrict__ WkTl,
    float* __restrict__ V, float* __restrict__ Sq, float* __restrict__ Phi)
{
    const int wave = blockIdx.x * 4 + (threadIdx.x >> 6);
    const int r0 = wave * 16;
    if (r0 >= N_NODES) return;
    const int lane = threadIdx.x & 63;
    const int m    = lane & 15;
    const int quad = lane >> 4;

    // A fragments, split hi/lo (K=128 -> 4 k-steps)
    bf16x8 Ah[4], Al[4];
    const float* xrow = x + (size_t)(r0 + m) * IN_DIM;
    #pragma unroll
    for (int t = 0; t < 4; ++t) {
        const float4 a = *(const float4*)(xrow + t * 32 + quad * 8);
        const float4 b = *(const float4*)(xrow + t * 32 + quad * 8 + 4);
        float vals[8] = {a.x, a.y, a.z, a.w, b.x, b.y, b.z, b.w};
        bf16x8 fh, fl;
        #pragma unroll
        for (int e = 0; e < 8; ++e) {
            const short hh = to_bf16(vals[e]);
            fh[e] = hh;
            fl[e] = to_bf16(vals[e] - bf16f(hh));
        }
        Ah[t] = fh; Al[t] = fl;
    }

    // ---- V = x @ Wv (16 col-tiles of 16) ----
    const unsigned short* bp = WvT + (size_t)m * IN_DIM + quad * 8;
    #pragma unroll
    for (int ct = 0; ct < 16; ++ct) {
        f32x4 acc = {0.f, 0.f, 0.f, 0.f};
        const unsigned short* bc = bp + (size_t)ct * 16 * IN_DIM;
        #pragma unroll
        for (int t = 0; t < 4; ++t) {
            bf16x8 B = *(const bf16x8*)(bc + t * 32);
            acc = __builtin_amdgcn_mfma_f32_16x16x32_bf16(Ah[t], B, acc, 0, 0, 0);
        }
        #pragma unroll
        for (int r = 0; r < 4; ++r)
            V[(size_t)(r0 + quad * 4 + r) * HD + ct * 16 + m] = acc[r];
    }

    // ---- q-path: proj = x @ Wqrf (64 cols, pair precision), then Sq ----
    #pragma unroll
    for (int ct = 0; ct < 4; ++ct) {
        const int c = ct * 16 + m;   // my C column
        const unsigned short* bh = WqTh + (size_t)c * IN_DIM + quad * 8;
        const unsigned short* bl = WqTl + (size_t)c * IN_DIM + quad * 8;
        bf16x8 Bh[4];
        #pragma unroll
        for (int t = 0; t < 4; ++t) Bh[t] = *(const bf16x8*)(bh + t * 32);
        f32x4 acc = {0.f, 0.f, 0.f, 0.f};
        #pragma unroll
        for (int t = 0; t < 4; ++t)
            acc = __builtin_amdgcn_mfma_f32_16x16x32_bf16(Ah[t], Bh[t], acc, 0, 0, 0);
        #pragma unroll
        for (int t = 0; t < 4; ++t)
            acc = __builtin_amdgcn_mfma_f32_16x16x32_bf16(Al[t], Bh[t], acc, 0, 0, 0);
        #pragma unroll
        for (int t = 0; t < 4; ++t) {
            bf16x8 Bl = *(const bf16x8*)(bl + t * 32);
            acc = __builtin_amdgcn_mfma_f32_16x16x32_bf16(Ah[t], Bl, acc, 0, 0, 0);
        }
        // epilogue: cos+sin, reduce over m-feature (low 3 bits of col)
        #pragma unroll
        for (int r = 0; r < 4; ++r) {
            float tv = __cosf(acc[r]) + __sinf(acc[r]);
            tv += __shfl_xor(tv, 1);
            tv += __shfl_xor(tv, 2);
            tv += __shfl_xor(tv, 4);
            if ((lane & 7) == 0) {
                const int h = ct * 2 + ((lane >> 3) & 1);
                Sq[(r0 + quad * 4 + r) * H_HEADS + h] = tv;
            }
        }
    }

    // ---- k-path: Phi for rows < 6250 (wave-uniform skip for 87.5%) ----
    if (r0 < K_NODES) {
        #pragma unroll
        for (int ct = 0; ct < 4; ++ct) {
            const int c = ct * 16 + m;
            const unsigned short* bh = WkTh + (size_t)c * IN_DIM + quad * 8;
            const unsigned short* bl = WkTl + (size_t)c * IN_DIM + quad * 8;
            bf16x8 Bh[4];
            #pragma unroll
            for (int t = 0; t < 4; ++t) Bh[t] = *(const bf16x8*)(bh + t * 32);
            f32x4 acc = {0.f, 0.f, 0.f, 0.f};
            #pragma unroll
            for (int t = 0; t < 4; ++t)
                acc = __builtin_amdgcn_mfma_f32_16x16x32_bf16(Ah[t], Bh[t], acc, 0, 0, 0);
            #pragma unroll
            for (int t = 0; t < 4; ++t)
                acc = __builtin_amdgcn_mfma_f32_16x16x32_bf16(Al[t], Bh[t], acc, 0, 0, 0);
            #pragma unroll
            for (int t = 0; t < 4; ++t) {
                bf16x8 Bl = *(const bf16x8*)(bl + t * 32);
                acc = __builtin_amdgcn_mfma_f32_16x16x32_bf16(Ah[t], Bl, acc, 0, 0, 0);
            }
            #pragma unroll
            for (int r = 0; r < 4; ++r) {
                const int row = r0 + quad * 4 + r;
                if (row < K_NODES)
                    Phi[(size_t)row * 64 + c] = __cosf(acc[r]) + __sinf(acc[r]);
            }
        }
    }
}

// ---------------------------------------------------------------------------
// Bucket edges by src (store dst) and by dst (store src|sign). 2 atomics/edge.
// ---------------------------------------------------------------------------
__global__ __launch_bounds__(256) void bucket_kernel(
    const int* __restrict__ src, const int* __restrict__ dst,
    const int* __restrict__ sign,
    int* __restrict__ srcCnt, int* __restrict__ srcBucket,
    int* __restrict__ dstCnt, unsigned* __restrict__ dstBucket)
{
    const int e = blockIdx.x * 256 + threadIdx.x;
    if (e >= E_EDGES) return;
    const int s = src[e];
    const int d = dst[e];
    const unsigned pos = (sign[e] == 1) ? 0x80000000u : 0u;

    const int ss = atomicAdd(&srcCnt[s], 1);
    if (ss < CAP) srcBucket[s * CAP + ss] = d;
    const int ds = atomicAdd(&dstCnt[d], 1);
    if (ds < CAP) dstBucket[d * CAP + ds] = (unsigned)s | pos;
}

// ---------------------------------------------------------------------------
// Gather-build pk_pos/pk_neg [N,8] and cnt_pos/cnt_neg [N]; thread per (dst,h).
// Phi flat index for flat row s = n*8+j, feature m:  s*8+m == n*64 + j*8 + m.
// ---------------------------------------------------------------------------
__global__ __launch_bounds__(256) void pk_kernel(
    const int* __restrict__ dstCnt, const unsigned* __restrict__ dstBucket,
    const float* __restrict__ Phi,
    float* __restrict__ pk_pos, float* __restrict__ pk_neg,
    float* __restrict__ cnt_pos, float* __restrict__ cnt_neg)
{
    const int t = blockIdx.x * 256 + threadIdx.x;
    if (t >= N_NODES * H_HEADS) return;
    const int d = t >> 3;
    const int h = t & 7;
    int deg = dstCnt[d];
    if (deg > CAP) deg = CAP;

    float accp = 0.f, accn = 0.f;
    int cp = 0, cn = 0;
    for (int i = 0; i < deg; ++i) {
        const unsigned entry = dstBucket[d * CAP + i];
        const int s = (int)(entry & 0x7FFFFFFFu);
        const float phi = Phi[s * H_HEADS + h];
        if (entry & 0x80000000u) { accp += phi; ++cp; }
        else                     { accn += phi; ++cn; }
    }
    pk_pos[t] = accp;
    pk_neg[t] = accn;
    if (h == 0) {
        cnt_pos[d] = (float)cp;
        cnt_neg[d] = (float)cn;
    }
}

// ---------------------------------------------------------------------------
// Gather-accumulate. One wave per src node (round-2 structure).
// ---------------------------------------------------------------------------
__global__ __launch_bounds__(256) void accum_kernel(
    const int* __restrict__ srcCnt, const int* __restrict__ srcBucket,
    const float* __restrict__ Sq,
    const float* __restrict__ pk_pos, const float* __restrict__ pk_neg,
    const float* __restrict__ cnt_pos, const float* __restrict__ cnt_neg,
    const float* __restrict__ V, float* __restrict__ out)
{
    const int s = blockIdx.x * 4 + (threadIdx.x >> 6);
    const int lane = threadIdx.x & 63;
    const int j = lane >> 3;       // edge slot within batch
    const int h = lane & 7;        // head for attn compute
    const int myhead = lane >> 3;  // head of my output columns (c=4*lane)

    int deg = srcCnt[s];
    if (deg > CAP) deg = CAP;
    const float sq = Sq[s * H_HEADS + h];

    float4 acc = make_float4(0.f, 0.f, 0.f, 0.f);
    const float4* __restrict__ V4 = (const float4*)V;

    for (int base = 0; base < deg; base += 8) {
        const int idx = base + j;
        const int dj = (idx < deg) ? srcBucket[s * CAP + idx] : 0;

        const float dp = fmaxf(cnt_pos[dj], 1.0f);
        const float dn = fmaxf(cnt_neg[dj], 1.0f);
        float np = sq * pk_pos[dj * H_HEADS + h] / dp;
        float nn = sq * pk_neg[dj * H_HEADS + h] / dn;

        float mp = np, mn = nn;
        mp = fmaxf(mp, __shfl_xor(mp, 1)); mn = fmaxf(mn, __shfl_xor(mn, 1));
        mp = fmaxf(mp, __shfl_xor(mp, 2)); mn = fmaxf(mn, __shfl_xor(mn, 2));
        mp = fmaxf(mp, __shfl_xor(mp, 4)); mn = fmaxf(mn, __shfl_xor(mn, 4));
        float ep = __expf(np - mp), en = __expf(nn - mn);
        float sp = ep, sn = en;
        sp += __shfl_xor(sp, 1); sn += __shfl_xor(sn, 1);
        sp += __shfl_xor(sp, 2); sn += __shfl_xor(sn, 2);
        sp += __shfl_xor(sp, 4); sn += __shfl_xor(sn, 4);
        const float a = ep / sp - en / sn;

        int nb = deg - base;
        if (nb > 8) nb = 8;
        for (int jj = 0; jj < nb; ++jj) {
            const int   dd = __shfl(dj, jj * 8);
            const float av = __shfl(a,  jj * 8 + myhead);
            const float4 vv = V4[dd * 64 + lane];
            acc.x = fmaf(vv.x, av, acc.x);
            acc.y = fmaf(vv.y, av, acc.y);
            acc.z = fmaf(vv.z, av, acc.z);
            acc.w = fmaf(vv.w, av, acc.w);
        }
    }
    ((float4*)out)[s * 64 + lane] = acc;   // every node written -> no memset
}

extern "C" void kernel_launch(void* const* d_in, const int* in_sizes, int n_in,
                              void* d_out, int out_size, void* d_ws, size_t ws_size,
                              hipStream_t stream) {
    const float* x   = (const float*)d_in[0];
    const float* Wq  = (const float*)d_in[1];
    const float* Wk  = (const float*)d_in[2];
    const float* Wv  = (const float*)d_in[3];
    const float* RF  = (const float*)d_in[4];
    const float* RFq = (const float*)d_in[5];
    const int* eidx  = (const int*)d_in[6];
    const int* esign = (const int*)d_in[7];
    const int* src = eidx;            // edge_index[0, :]
    const int* dst = eidx + E_EDGES;  // edge_index[1, :]
    float* out = (float*)d_out;

    // Workspace layout: V | Sq | Phi | pk_pos | pk_neg | cnt_pos | cnt_neg |
    //                   srcCnt | dstCnt | srcBucket | dstBucket | bf16 weights
    float* ws      = (float*)d_ws;
    float* V       = ws;                                  // N*256
    float* Sq      = V + (size_t)N_NODES * HD;            // N*8
    float* Phi     = Sq + (size_t)N_NODES * H_HEADS;      // 6250*64 = 400000
    float* pk_pos  = Phi + (size_t)N_NODES * M_FEAT;      // N*8
    float* pk_neg  = pk_pos + (size_t)N_NODES * H_HEADS;  // N*8
    float* cnt_pos = pk_neg + (size_t)N_NODES * H_HEADS;  // N
    float* cnt_neg = cnt_pos + N_NODES;                   // N
    int* srcCnt    = (int*)(cnt_neg + N_NODES);           // N
    int* dstCnt    = srcCnt + N_NODES;                    // N
    int* srcBucket = dstCnt + N_NODES;                    // N*CAP
    unsigned* dstBucket = (unsigned*)(srcBucket + (size_t)N_NODES * CAP); // N*CAP
    unsigned short* WqTh = (unsigned short*)(dstBucket + (size_t)N_NODES * CAP);
    unsigned short* WqTl = WqTh + 64 * IN_DIM;            // 8192 each
    unsigned short* WkTh = WqTl + 64 * IN_DIM;
    unsigned short* WkTl = WkTh + 64 * IN_DIM;
    unsigned short* WvT  = WkTl + 64 * IN_DIM;            // 256*128

    // Zero only the bucket counters (contiguous 2*N ints).
    hipMemsetAsync(srcCnt, 0, sizeof(int) * (size_t)N_NODES * 2, stream);

    prep_kernel<<<192, 256, 0, stream>>>(Wq, Wk, Wv, RF, RFq,
                                         WqTh, WqTl, WkTh, WkTl, WvT);
    bucket_kernel<<<(E_EDGES + 255) / 256, 256, 0, stream>>>(
        src, dst, esign, srcCnt, srcBucket, dstCnt, dstBucket);
    xform_kernel<<<(N_NODES / 16 + 3) / 4, 256, 0, stream>>>(
        x, WvT, WqTh, WqTl, WkTh, WkTl, V, Sq, Phi);
    pk_kernel<<<(N_NODES * H_HEADS + 255) / 256, 256, 0, stream>>>(
        dstCnt, dstBucket, Phi, pk_pos, pk_neg, cnt_pos, cnt_neg);
    accum_kernel<<<N_NODES / 4, 256, 0, stream>>>(
        srcCnt, srcBucket, Sq, pk_pos, pk_neg, cnt_pos, cnt_neg, V, out);
}

// Round 6
// 256.915 us; speedup vs baseline: 1.4216x; 1.0807x over previous
//
#include <hip/hip_runtime.h>

// Problem constants (fixed by the reference)
constexpr int N_NODES = 50000;
constexpr int E_EDGES = 400000;
constexpr int IN_DIM  = 128;
constexpr int HD      = 256;   // H*D
constexpr int H_HEADS = 8;
constexpr int D_HEAD  = 32;
constexpr int M_FEAT  = 8;
constexpr int K_NODES = N_NODES / H_HEADS;   // 6250 nodes need Phi
constexpr int CAP     = 48;    // bucket capacity; deg ~ Poisson(8), P(>=48) ~ 1e-23

typedef __attribute__((ext_vector_type(8))) short bf16x8;
typedef __attribute__((ext_vector_type(4))) float f32x4;

__device__ inline short to_bf16(float f) {
    unsigned u = __builtin_bit_cast(unsigned, f);
    u += 0x7FFFu + ((u >> 16) & 1u);   // RNE; inputs are finite
    return (short)(u >> 16);
}
__device__ inline float bf16f(short h) {
    return __builtin_bit_cast(float, (unsigned)(unsigned short)h << 16);
}

// ---------------------------------------------------------------------------
// Prep kernel.
//   blocks [0,32):   Wqrf[d][c=h*8+m] = sum_dd Wq[d][h*32+dd]*RFq[dd][m],
//                    stored split-bf16 transposed: WqTh/WqTl[c*128+d]
//   blocks [32,64):  same for Wk x RF -> WkTh/WkTl
//   blocks [64,192): WvT[n*128+d] = bf16(Wv[d][n])   (col-major B layout)
// ---------------------------------------------------------------------------
__global__ __launch_bounds__(256) void prep_kernel(
    const float* __restrict__ Wq, const float* __restrict__ Wk,
    const float* __restrict__ Wv, const float* __restrict__ RF,
    const float* __restrict__ RFq,
    unsigned short* __restrict__ WqTh, unsigned short* __restrict__ WqTl,
    unsigned short* __restrict__ WkTh, unsigned short* __restrict__ WkTl,
    unsigned short* __restrict__ WvT)
{
    const int b = blockIdx.x;
    const int t = threadIdx.x;
    if (b < 64) {
        const bool isQ = (b < 32);
        const int idx = (isQ ? b : b - 32) * 256 + t;   // 0..8191
        const int d = idx >> 6;
        const int c = idx & 63;
        const int hj = c >> 3, m = c & 7;
        const float* W = isQ ? Wq : Wk;
        const float* R = isQ ? RFq : RF;
        float acc = 0.f;
        #pragma unroll
        for (int dd = 0; dd < D_HEAD; ++dd)
            acc = fmaf(W[d * HD + hj * D_HEAD + dd], R[dd * M_FEAT + m], acc);
        const short h = to_bf16(acc);
        const short l = to_bf16(acc - bf16f(h));
        (isQ ? WqTh : WkTh)[c * IN_DIM + d] = (unsigned short)h;
        (isQ ? WqTl : WkTl)[c * IN_DIM + d] = (unsigned short)l;
    } else {
        const int idx = (b - 64) * 256 + t;             // 0..32767
        const int n = idx >> 7;
        const int d = idx & 127;
        WvT[idx] = (unsigned short)to_bf16(Wv[d * HD + n]);
    }
}

// ---------------------------------------------------------------------------
// Fused transform kernel (one x pass). One wave per 16 rows.
//   Vb[r,0:256] = bf16(x @ Wv)       (single bf16 MFMA, fp32 acc, bf16 store)
//   Sq[r,h]     = sum_m cos+sin(x @ Wqrf)   (bf16-PAIR MFMA: Ah*Bh+Al*Bh+Ah*Bl)
//   Phi[r,0:64] = cos+sin(x @ Wkrf)  for r < 6250   (pair MFMA)
// Fragment maps (verified round 4): A[m=lane&15][k=quad*8+j],
// B[k=quad*8+j][n=lane&15] (col-major, k-contig), C col=lane&15 row=quad*4+r.
// ---------------------------------------------------------------------------
__global__ __launch_bounds__(256) void xform_kernel(
    const float* __restrict__ x, const unsigned short* __restrict__ WvT,
    const unsigned short* __restrict__ WqTh, const unsigned short* __restrict__ WqTl,
    const unsigned short* __restrict__ WkTh, const unsigned short* __restrict__ WkTl,
    unsigned short* __restrict__ Vb, float* __restrict__ Sq, float* __restrict__ Phi)
{
    const int wave = blockIdx.x * 4 + (threadIdx.x >> 6);
    const int r0 = wave * 16;
    if (r0 >= N_NODES) return;
    const int lane = threadIdx.x & 63;
    const int m    = lane & 15;
    const int quad = lane >> 4;

    // A fragments, split hi/lo (K=128 -> 4 k-steps)
    bf16x8 Ah[4], Al[4];
    const float* xrow = x + (size_t)(r0 + m) * IN_DIM;
    #pragma unroll
    for (int t = 0; t < 4; ++t) {
        const float4 a = *(const float4*)(xrow + t * 32 + quad * 8);
        const float4 b = *(const float4*)(xrow + t * 32 + quad * 8 + 4);
        float vals[8] = {a.x, a.y, a.z, a.w, b.x, b.y, b.z, b.w};
        bf16x8 fh, fl;
        #pragma unroll
        for (int e = 0; e < 8; ++e) {
            const short hh = to_bf16(vals[e]);
            fh[e] = hh;
            fl[e] = to_bf16(vals[e] - bf16f(hh));
        }
        Ah[t] = fh; Al[t] = fl;
    }

    // ---- V = x @ Wv (16 col-tiles of 16), stored bf16 ----
    const unsigned short* bp = WvT + (size_t)m * IN_DIM + quad * 8;
    #pragma unroll
    for (int ct = 0; ct < 16; ++ct) {
        f32x4 acc = {0.f, 0.f, 0.f, 0.f};
        const unsigned short* bc = bp + (size_t)ct * 16 * IN_DIM;
        #pragma unroll
        for (int t = 0; t < 4; ++t) {
            bf16x8 B = *(const bf16x8*)(bc + t * 32);
            acc = __builtin_amdgcn_mfma_f32_16x16x32_bf16(Ah[t], B, acc, 0, 0, 0);
        }
        #pragma unroll
        for (int r = 0; r < 4; ++r)
            Vb[(size_t)(r0 + quad * 4 + r) * HD + ct * 16 + m] =
                (unsigned short)to_bf16(acc[r]);
    }

    // ---- q-path: proj = x @ Wqrf (64 cols, pair precision), then Sq ----
    #pragma unroll
    for (int ct = 0; ct < 4; ++ct) {
        const int c = ct * 16 + m;   // my C column
        const unsigned short* bh = WqTh + (size_t)c * IN_DIM + quad * 8;
        const unsigned short* bl = WqTl + (size_t)c * IN_DIM + quad * 8;
        bf16x8 Bh[4];
        #pragma unroll
        for (int t = 0; t < 4; ++t) Bh[t] = *(const bf16x8*)(bh + t * 32);
        f32x4 acc = {0.f, 0.f, 0.f, 0.f};
        #pragma unroll
        for (int t = 0; t < 4; ++t)
            acc = __builtin_amdgcn_mfma_f32_16x16x32_bf16(Ah[t], Bh[t], acc, 0, 0, 0);
        #pragma unroll
        for (int t = 0; t < 4; ++t)
            acc = __builtin_amdgcn_mfma_f32_16x16x32_bf16(Al[t], Bh[t], acc, 0, 0, 0);
        #pragma unroll
        for (int t = 0; t < 4; ++t) {
            bf16x8 Bl = *(const bf16x8*)(bl + t * 32);
            acc = __builtin_amdgcn_mfma_f32_16x16x32_bf16(Ah[t], Bl, acc, 0, 0, 0);
        }
        // epilogue: cos+sin, reduce over m-feature (low 3 bits of col)
        #pragma unroll
        for (int r = 0; r < 4; ++r) {
            float tv = __cosf(acc[r]) + __sinf(acc[r]);
            tv += __shfl_xor(tv, 1);
            tv += __shfl_xor(tv, 2);
            tv += __shfl_xor(tv, 4);
            if ((lane & 7) == 0) {
                const int h = ct * 2 + ((lane >> 3) & 1);
                Sq[(r0 + quad * 4 + r) * H_HEADS + h] = tv;
            }
        }
    }

    // ---- k-path: Phi for rows < 6250 (wave-uniform skip for 87.5%) ----
    if (r0 < K_NODES) {
        #pragma unroll
        for (int ct = 0; ct < 4; ++ct) {
            const int c = ct * 16 + m;
            const unsigned short* bh = WkTh + (size_t)c * IN_DIM + quad * 8;
            const unsigned short* bl = WkTl + (size_t)c * IN_DIM + quad * 8;
            bf16x8 Bh[4];
            #pragma unroll
            for (int t = 0; t < 4; ++t) Bh[t] = *(const bf16x8*)(bh + t * 32);
            f32x4 acc = {0.f, 0.f, 0.f, 0.f};
            #pragma unroll
            for (int t = 0; t < 4; ++t)
                acc = __builtin_amdgcn_mfma_f32_16x16x32_bf16(Ah[t], Bh[t], acc, 0, 0, 0);
            #pragma unroll
            for (int t = 0; t < 4; ++t)
                acc = __builtin_amdgcn_mfma_f32_16x16x32_bf16(Al[t], Bh[t], acc, 0, 0, 0);
            #pragma unroll
            for (int t = 0; t < 4; ++t) {
                bf16x8 Bl = *(const bf16x8*)(bl + t * 32);
                acc = __builtin_amdgcn_mfma_f32_16x16x32_bf16(Ah[t], Bl, acc, 0, 0, 0);
            }
            #pragma unroll
            for (int r = 0; r < 4; ++r) {
                const int row = r0 + quad * 4 + r;
                if (row < K_NODES)
                    Phi[(size_t)row * 64 + c] = __cosf(acc[r]) + __sinf(acc[r]);
            }
        }
    }
}

// ---------------------------------------------------------------------------
// Bucket edges by src (store dst) and by dst (store src|sign). 2 atomics/edge.
// ---------------------------------------------------------------------------
__global__ __launch_bounds__(256) void bucket_kernel(
    const int* __restrict__ src, const int* __restrict__ dst,
    const int* __restrict__ sign,
    int* __restrict__ srcCnt, int* __restrict__ srcBucket,
    int* __restrict__ dstCnt, unsigned* __restrict__ dstBucket)
{
    const int e = blockIdx.x * 256 + threadIdx.x;
    if (e >= E_EDGES) return;
    const int s = src[e];
    const int d = dst[e];
    const unsigned pos = (sign[e] == 1) ? 0x80000000u : 0u;

    const int ss = atomicAdd(&srcCnt[s], 1);
    if (ss < CAP) srcBucket[s * CAP + ss] = d;
    const int ds = atomicAdd(&dstCnt[d], 1);
    if (ds < CAP) dstBucket[d * CAP + ds] = (unsigned)s | pos;
}

// ---------------------------------------------------------------------------
// Gather-build pk_pos/pk_neg [N,8] and cnt_pos/cnt_neg [N]; thread per (dst,h).
// Phi flat index for flat row s = n*8+j, feature m:  s*8+m == n*64 + j*8 + m.
// ---------------------------------------------------------------------------
__global__ __launch_bounds__(256) void pk_kernel(
    const int* __restrict__ dstCnt, const unsigned* __restrict__ dstBucket,
    const float* __restrict__ Phi,
    float* __restrict__ pk_pos, float* __restrict__ pk_neg,
    float* __restrict__ cnt_pos, float* __restrict__ cnt_neg)
{
    const int t = blockIdx.x * 256 + threadIdx.x;
    if (t >= N_NODES * H_HEADS) return;
    const int d = t >> 3;
    const int h = t & 7;
    int deg = dstCnt[d];
    if (deg > CAP) deg = CAP;

    float accp = 0.f, accn = 0.f;
    int cp = 0, cn = 0;
    for (int i = 0; i < deg; ++i) {
        const unsigned entry = dstBucket[d * CAP + i];
        const int s = (int)(entry & 0x7FFFFFFFu);
        const float phi = Phi[s * H_HEADS + h];
        if (entry & 0x80000000u) { accp += phi; ++cp; }
        else                     { accn += phi; ++cn; }
    }
    pk_pos[t] = accp;
    pk_neg[t] = accn;
    if (h == 0) {
        cnt_pos[d] = (float)cp;
        cnt_neg[d] = (float)cn;
    }
}

// ---------------------------------------------------------------------------
// Gather-accumulate. One wave per src node. V gathered as bf16 (ushort4 = 8 B
// per lane, 512 B per row per wave, coalesced), fp32 accumulate.
// ---------------------------------------------------------------------------
__global__ __launch_bounds__(256) void accum_kernel(
    const int* __restrict__ srcCnt, const int* __restrict__ srcBucket,
    const float* __restrict__ Sq,
    const float* __restrict__ pk_pos, const float* __restrict__ pk_neg,
    const float* __restrict__ cnt_pos, const float* __restrict__ cnt_neg,
    const unsigned short* __restrict__ Vb, float* __restrict__ out)
{
    const int s = blockIdx.x * 4 + (threadIdx.x >> 6);
    const int lane = threadIdx.x & 63;
    const int j = lane >> 3;       // edge slot within batch
    const int h = lane & 7;        // head for attn compute
    const int myhead = lane >> 3;  // head of my output columns (c=4*lane)

    int deg = srcCnt[s];
    if (deg > CAP) deg = CAP;
    const float sq = Sq[s * H_HEADS + h];

    float4 acc = make_float4(0.f, 0.f, 0.f, 0.f);
    const ushort4* __restrict__ V4 = (const ushort4*)Vb;   // 64 ushort4 per row

    for (int base = 0; base < deg; base += 8) {
        const int idx = base + j;
        const int dj = (idx < deg) ? srcBucket[s * CAP + idx] : 0;

        const float dp = fmaxf(cnt_pos[dj], 1.0f);
        const float dn = fmaxf(cnt_neg[dj], 1.0f);
        float np = sq * pk_pos[dj * H_HEADS + h] / dp;
        float nn = sq * pk_neg[dj * H_HEADS + h] / dn;

        float mp = np, mn = nn;
        mp = fmaxf(mp, __shfl_xor(mp, 1)); mn = fmaxf(mn, __shfl_xor(mn, 1));
        mp = fmaxf(mp, __shfl_xor(mp, 2)); mn = fmaxf(mn, __shfl_xor(mn, 2));
        mp = fmaxf(mp, __shfl_xor(mp, 4)); mn = fmaxf(mn, __shfl_xor(mn, 4));
        float ep = __expf(np - mp), en = __expf(nn - mn);
        float sp = ep, sn = en;
        sp += __shfl_xor(sp, 1); sn += __shfl_xor(sn, 1);
        sp += __shfl_xor(sp, 2); sn += __shfl_xor(sn, 2);
        sp += __shfl_xor(sp, 4); sn += __shfl_xor(sn, 4);
        const float a = ep / sp - en / sn;

        int nb = deg - base;
        if (nb > 8) nb = 8;
        for (int jj = 0; jj < nb; ++jj) {
            const int   dd = __shfl(dj, jj * 8);
            const float av = __shfl(a,  jj * 8 + myhead);
            const ushort4 vv = V4[dd * 64 + lane];
            acc.x = fmaf(bf16f((short)vv.x), av, acc.x);
            acc.y = fmaf(bf16f((short)vv.y), av, acc.y);
            acc.z = fmaf(bf16f((short)vv.z), av, acc.z);
            acc.w = fmaf(bf16f((short)vv.w), av, acc.w);
        }
    }
    ((float4*)out)[s * 64 + lane] = acc;   // every node written -> no memset
}

extern "C" void kernel_launch(void* const* d_in, const int* in_sizes, int n_in,
                              void* d_out, int out_size, void* d_ws, size_t ws_size,
                              hipStream_t stream) {
    const float* x   = (const float*)d_in[0];
    const float* Wq  = (const float*)d_in[1];
    const float* Wk  = (const float*)d_in[2];
    const float* Wv  = (const float*)d_in[3];
    const float* RF  = (const float*)d_in[4];
    const float* RFq = (const float*)d_in[5];
    const int* eidx  = (const int*)d_in[6];
    const int* esign = (const int*)d_in[7];
    const int* src = eidx;            // edge_index[0, :]
    const int* dst = eidx + E_EDGES;  // edge_index[1, :]
    float* out = (float*)d_out;

    // Workspace layout: Vb(bf16, in N*256-float region) | Sq | Phi | pk_pos |
    //   pk_neg | cnt_pos | cnt_neg | srcCnt | dstCnt | srcBucket | dstBucket |
    //   bf16 weights
    float* ws      = (float*)d_ws;
    unsigned short* Vb = (unsigned short*)ws;             // N*256 bf16 (uses half region)
    float* Sq      = ws + (size_t)N_NODES * HD;           // N*8
    float* Phi     = Sq + (size_t)N_NODES * H_HEADS;      // 6250*64 = 400000
    float* pk_pos  = Phi + (size_t)N_NODES * M_FEAT;      // N*8
    float* pk_neg  = pk_pos + (size_t)N_NODES * H_HEADS;  // N*8
    float* cnt_pos = pk_neg + (size_t)N_NODES * H_HEADS;  // N
    float* cnt_neg = cnt_pos + N_NODES;                   // N
    int* srcCnt    = (int*)(cnt_neg + N_NODES);           // N
    int* dstCnt    = srcCnt + N_NODES;                    // N
    int* srcBucket = dstCnt + N_NODES;                    // N*CAP
    unsigned* dstBucket = (unsigned*)(srcBucket + (size_t)N_NODES * CAP); // N*CAP
    unsigned short* WqTh = (unsigned short*)(dstBucket + (size_t)N_NODES * CAP);
    unsigned short* WqTl = WqTh + 64 * IN_DIM;            // 8192 each
    unsigned short* WkTh = WqTl + 64 * IN_DIM;
    unsigned short* WkTl = WkTh + 64 * IN_DIM;
    unsigned short* WvT  = WkTl + 64 * IN_DIM;            // 256*128

    // Zero only the bucket counters (contiguous 2*N ints).
    hipMemsetAsync(srcCnt, 0, sizeof(int) * (size_t)N_NODES * 2, stream);

    prep_kernel<<<192, 256, 0, stream>>>(Wq, Wk, Wv, RF, RFq,
                                         WqTh, WqTl, WkTh, WkTl, WvT);
    bucket_kernel<<<(E_EDGES + 255) / 256, 256, 0, stream>>>(
        src, dst, esign, srcCnt, srcBucket, dstCnt, dstBucket);
    xform_kernel<<<(N_NODES / 16 + 3) / 4, 256, 0, stream>>>(
        x, WvT, WqTh, WqTl, WkTh, WkTl, Vb, Sq, Phi);
    pk_kernel<<<(N_NODES * H_HEADS + 255) / 256, 256, 0, stream>>>(
        dstCnt, dstBucket, Phi, pk_pos, pk_neg, cnt_pos, cnt_neg);
    accum_kernel<<<N_NODES / 4, 256, 0, stream>>>(
        srcCnt, srcBucket, Sq, pk_pos, pk_neg, cnt_pos, cnt_neg, Vb, out);
}

// Round 7
// 254.566 us; speedup vs baseline: 1.4347x; 1.0092x over previous
//
#include <hip/hip_runtime.h>

// Problem constants (fixed by the reference)
constexpr int N_NODES = 50000;
constexpr int E_EDGES = 400000;
constexpr int IN_DIM  = 128;
constexpr int HD      = 256;   // H*D
constexpr int H_HEADS = 8;
constexpr int D_HEAD  = 32;
constexpr int M_FEAT  = 8;
constexpr int K_NODES = N_NODES / H_HEADS;   // 6250 nodes need Phi
constexpr int CAP     = 48;    // bucket capacity; deg ~ Poisson(8), P(>=48) ~ 1e-23

typedef __attribute__((ext_vector_type(8))) short bf16x8;
typedef __attribute__((ext_vector_type(4))) float f32x4;

__device__ inline short to_bf16(float f) {
    unsigned u = __builtin_bit_cast(unsigned, f);
    u += 0x7FFFu + ((u >> 16) & 1u);   // RNE; inputs are finite
    return (short)(u >> 16);
}
__device__ inline float bf16f(short h) {
    return __builtin_bit_cast(float, (unsigned)(unsigned short)h << 16);
}

// ---------------------------------------------------------------------------
// Prep kernel.
//   blocks [0,32):   Wqrf[d][c=h*8+m] = sum_dd Wq[d][h*32+dd]*RFq[dd][m],
//                    stored split-bf16 transposed: WqTh/WqTl[c*128+d]
//   blocks [32,64):  same for Wk x RF -> WkTh/WkTl
//   blocks [64,192): WvT[n*128+d] = bf16(Wv[d][n])   (col-major B layout)
// ---------------------------------------------------------------------------
__global__ __launch_bounds__(256) void prep_kernel(
    const float* __restrict__ Wq, const float* __restrict__ Wk,
    const float* __restrict__ Wv, const float* __restrict__ RF,
    const float* __restrict__ RFq,
    unsigned short* __restrict__ WqTh, unsigned short* __restrict__ WqTl,
    unsigned short* __restrict__ WkTh, unsigned short* __restrict__ WkTl,
    unsigned short* __restrict__ WvT)
{
    const int b = blockIdx.x;
    const int t = threadIdx.x;
    if (b < 64) {
        const bool isQ = (b < 32);
        const int idx = (isQ ? b : b - 32) * 256 + t;   // 0..8191
        const int d = idx >> 6;
        const int c = idx & 63;
        const int hj = c >> 3, m = c & 7;
        const float* W = isQ ? Wq : Wk;
        const float* R = isQ ? RFq : RF;
        float acc = 0.f;
        #pragma unroll
        for (int dd = 0; dd < D_HEAD; ++dd)
            acc = fmaf(W[d * HD + hj * D_HEAD + dd], R[dd * M_FEAT + m], acc);
        const short h = to_bf16(acc);
        const short l = to_bf16(acc - bf16f(h));
        (isQ ? WqTh : WkTh)[c * IN_DIM + d] = (unsigned short)h;
        (isQ ? WqTl : WkTl)[c * IN_DIM + d] = (unsigned short)l;
    } else {
        const int idx = (b - 64) * 256 + t;             // 0..32767
        const int n = idx >> 7;
        const int d = idx & 127;
        WvT[idx] = (unsigned short)to_bf16(Wv[d * HD + n]);
    }
}

// ---------------------------------------------------------------------------
// Fused transform kernel. One BLOCK per 16-row tile; the 4 waves split the
// column work (wave w: V col-tiles 4w..4w+3, q col-tile w, k col-tile w).
// 3125 blocks -> 12500 waves -> full occupancy; per-wave serial chain is 4x
// shorter than the round-5 version (which was latency-bound at 25% occ).
// Fragment maps (verified round 4): A[m=lane&15][k=quad*8+j],
// B[k=quad*8+j][n=lane&15] (col-major, k-contig), C col=lane&15 row=quad*4+r.
// ---------------------------------------------------------------------------
__global__ __launch_bounds__(256) void xform_kernel(
    const float* __restrict__ x, const unsigned short* __restrict__ WvT,
    const unsigned short* __restrict__ WqTh, const unsigned short* __restrict__ WqTl,
    const unsigned short* __restrict__ WkTh, const unsigned short* __restrict__ WkTl,
    unsigned short* __restrict__ Vb, float* __restrict__ Sq, float* __restrict__ Phi)
{
    const int r0   = blockIdx.x * 16;
    const int w    = threadIdx.x >> 6;   // wave id 0..3 = column group
    const int lane = threadIdx.x & 63;
    const int m    = lane & 15;
    const int quad = lane >> 4;

    // A fragments, split hi/lo (K=128 -> 4 k-steps). Each wave loads the same
    // 16 rows (8 KB); L1 serves the repeats.
    bf16x8 Ah[4], Al[4];
    const float* xrow = x + (size_t)(r0 + m) * IN_DIM;
    #pragma unroll
    for (int t = 0; t < 4; ++t) {
        const float4 a = *(const float4*)(xrow + t * 32 + quad * 8);
        const float4 b = *(const float4*)(xrow + t * 32 + quad * 8 + 4);
        float vals[8] = {a.x, a.y, a.z, a.w, b.x, b.y, b.z, b.w};
        bf16x8 fh, fl;
        #pragma unroll
        for (int e = 0; e < 8; ++e) {
            const short hh = to_bf16(vals[e]);
            fh[e] = hh;
            fl[e] = to_bf16(vals[e] - bf16f(hh));
        }
        Ah[t] = fh; Al[t] = fl;
    }

    // ---- V = x @ Wv: this wave's 4 col-tiles (4 independent MFMA chains) ----
    const unsigned short* bp = WvT + (size_t)m * IN_DIM + quad * 8;
    #pragma unroll
    for (int i = 0; i < 4; ++i) {
        const int ct = w * 4 + i;
        f32x4 acc = {0.f, 0.f, 0.f, 0.f};
        const unsigned short* bc = bp + (size_t)ct * 16 * IN_DIM;
        #pragma unroll
        for (int t = 0; t < 4; ++t) {
            bf16x8 B = *(const bf16x8*)(bc + t * 32);
            acc = __builtin_amdgcn_mfma_f32_16x16x32_bf16(Ah[t], B, acc, 0, 0, 0);
        }
        #pragma unroll
        for (int r = 0; r < 4; ++r)
            Vb[(size_t)(r0 + quad * 4 + r) * HD + ct * 16 + m] =
                (unsigned short)to_bf16(acc[r]);
    }

    // ---- q-path: col-tile w (pair precision, 2 parallel chains), then Sq ----
    {
        const int c = w * 16 + m;   // my C column
        const unsigned short* bh = WqTh + (size_t)c * IN_DIM + quad * 8;
        const unsigned short* bl = WqTl + (size_t)c * IN_DIM + quad * 8;
        bf16x8 Bh[4];
        #pragma unroll
        for (int t = 0; t < 4; ++t) Bh[t] = *(const bf16x8*)(bh + t * 32);
        f32x4 acc1 = {0.f, 0.f, 0.f, 0.f};
        f32x4 acc2 = {0.f, 0.f, 0.f, 0.f};
        #pragma unroll
        for (int t = 0; t < 4; ++t) {
            acc1 = __builtin_amdgcn_mfma_f32_16x16x32_bf16(Ah[t], Bh[t], acc1, 0, 0, 0);
            acc2 = __builtin_amdgcn_mfma_f32_16x16x32_bf16(Al[t], Bh[t], acc2, 0, 0, 0);
        }
        #pragma unroll
        for (int t = 0; t < 4; ++t) {
            bf16x8 Bl = *(const bf16x8*)(bl + t * 32);
            acc2 = __builtin_amdgcn_mfma_f32_16x16x32_bf16(Ah[t], Bl, acc2, 0, 0, 0);
        }
        #pragma unroll
        for (int r = 0; r < 4; ++r) {
            const float pv = acc1[r] + acc2[r];
            float tv = __cosf(pv) + __sinf(pv);
            tv += __shfl_xor(tv, 1);
            tv += __shfl_xor(tv, 2);
            tv += __shfl_xor(tv, 4);
            if ((lane & 7) == 0) {
                const int h = w * 2 + (m >> 3);
                Sq[(r0 + quad * 4 + r) * H_HEADS + h] = tv;
            }
        }
    }

    // ---- k-path: col-tile w, Phi for rows < 6250 (wave-uniform skip) ----
    if (r0 < K_NODES) {
        const int c = w * 16 + m;
        const unsigned short* bh = WkTh + (size_t)c * IN_DIM + quad * 8;
        const unsigned short* bl = WkTl + (size_t)c * IN_DIM + quad * 8;
        bf16x8 Bh[4];
        #pragma unroll
        for (int t = 0; t < 4; ++t) Bh[t] = *(const bf16x8*)(bh + t * 32);
        f32x4 acc1 = {0.f, 0.f, 0.f, 0.f};
        f32x4 acc2 = {0.f, 0.f, 0.f, 0.f};
        #pragma unroll
        for (int t = 0; t < 4; ++t) {
            acc1 = __builtin_amdgcn_mfma_f32_16x16x32_bf16(Ah[t], Bh[t], acc1, 0, 0, 0);
            acc2 = __builtin_amdgcn_mfma_f32_16x16x32_bf16(Al[t], Bh[t], acc2, 0, 0, 0);
        }
        #pragma unroll
        for (int t = 0; t < 4; ++t) {
            bf16x8 Bl = *(const bf16x8*)(bl + t * 32);
            acc2 = __builtin_amdgcn_mfma_f32_16x16x32_bf16(Ah[t], Bl, acc2, 0, 0, 0);
        }
        #pragma unroll
        for (int r = 0; r < 4; ++r) {
            const int row = r0 + quad * 4 + r;
            if (row < K_NODES)
                Phi[(size_t)row * 64 + c] = __cosf(acc1[r] + acc2[r]) + __sinf(acc1[r] + acc2[r]);
        }
    }
}

// ---------------------------------------------------------------------------
// Bucket edges by src (store dst) and by dst (store src|sign). 2 atomics/edge.
// ---------------------------------------------------------------------------
__global__ __launch_bounds__(256) void bucket_kernel(
    const int* __restrict__ src, const int* __restrict__ dst,
    const int* __restrict__ sign,
    int* __restrict__ srcCnt, int* __restrict__ srcBucket,
    int* __restrict__ dstCnt, unsigned* __restrict__ dstBucket)
{
    const int e = blockIdx.x * 256 + threadIdx.x;
    if (e >= E_EDGES) return;
    const int s = src[e];
    const int d = dst[e];
    const unsigned pos = (sign[e] == 1) ? 0x80000000u : 0u;

    const int ss = atomicAdd(&srcCnt[s], 1);
    if (ss < CAP) srcBucket[s * CAP + ss] = d;
    const int ds = atomicAdd(&dstCnt[d], 1);
    if (ds < CAP) dstBucket[d * CAP + ds] = (unsigned)s | pos;
}

// ---------------------------------------------------------------------------
// Gather-build pk_pos/pk_neg [N,8] and cnt_pos/cnt_neg [N]; thread per (dst,h).
// Phi flat index for flat row s = n*8+j, feature m:  s*8+m == n*64 + j*8 + m.
// ---------------------------------------------------------------------------
__global__ __launch_bounds__(256) void pk_kernel(
    const int* __restrict__ dstCnt, const unsigned* __restrict__ dstBucket,
    const float* __restrict__ Phi,
    float* __restrict__ pk_pos, float* __restrict__ pk_neg,
    float* __restrict__ cnt_pos, float* __restrict__ cnt_neg)
{
    const int t = blockIdx.x * 256 + threadIdx.x;
    if (t >= N_NODES * H_HEADS) return;
    const int d = t >> 3;
    const int h = t & 7;
    int deg = dstCnt[d];
    if (deg > CAP) deg = CAP;

    float accp = 0.f, accn = 0.f;
    int cp = 0, cn = 0;
    for (int i = 0; i < deg; ++i) {
        const unsigned entry = dstBucket[d * CAP + i];
        const int s = (int)(entry & 0x7FFFFFFFu);
        const float phi = Phi[s * H_HEADS + h];
        if (entry & 0x80000000u) { accp += phi; ++cp; }
        else                     { accn += phi; ++cn; }
    }
    pk_pos[t] = accp;
    pk_neg[t] = accn;
    if (h == 0) {
        cnt_pos[d] = (float)cp;
        cnt_neg[d] = (float)cn;
    }
}

// ---------------------------------------------------------------------------
// Gather-accumulate. One wave per src node. V gathered as bf16 (ushort4 = 8 B
// per lane, 512 B per row per wave, coalesced), fp32 accumulate.
// ---------------------------------------------------------------------------
__global__ __launch_bounds__(256) void accum_kernel(
    const int* __restrict__ srcCnt, const int* __restrict__ srcBucket,
    const float* __restrict__ Sq,
    const float* __restrict__ pk_pos, const float* __restrict__ pk_neg,
    const float* __restrict__ cnt_pos, const float* __restrict__ cnt_neg,
    const unsigned short* __restrict__ Vb, float* __restrict__ out)
{
    const int s = blockIdx.x * 4 + (threadIdx.x >> 6);
    const int lane = threadIdx.x & 63;
    const int j = lane >> 3;       // edge slot within batch
    const int h = lane & 7;        // head for attn compute
    const int myhead = lane >> 3;  // head of my output columns (c=4*lane)

    int deg = srcCnt[s];
    if (deg > CAP) deg = CAP;
    const float sq = Sq[s * H_HEADS + h];

    float4 acc = make_float4(0.f, 0.f, 0.f, 0.f);
    const ushort4* __restrict__ V4 = (const ushort4*)Vb;   // 64 ushort4 per row

    for (int base = 0; base < deg; base += 8) {
        const int idx = base + j;
        const int dj = (idx < deg) ? srcBucket[s * CAP + idx] : 0;

        const float dp = fmaxf(cnt_pos[dj], 1.0f);
        const float dn = fmaxf(cnt_neg[dj], 1.0f);
        float np = sq * pk_pos[dj * H_HEADS + h] / dp;
        float nn = sq * pk_neg[dj * H_HEADS + h] / dn;

        float mp = np, mn = nn;
        mp = fmaxf(mp, __shfl_xor(mp, 1)); mn = fmaxf(mn, __shfl_xor(mn, 1));
        mp = fmaxf(mp, __shfl_xor(mp, 2)); mn = fmaxf(mn, __shfl_xor(mn, 2));
        mp = fmaxf(mp, __shfl_xor(mp, 4)); mn = fmaxf(mn, __shfl_xor(mn, 4));
        float ep = __expf(np - mp), en = __expf(nn - mn);
        float sp = ep, sn = en;
        sp += __shfl_xor(sp, 1); sn += __shfl_xor(sn, 1);
        sp += __shfl_xor(sp, 2); sn += __shfl_xor(sn, 2);
        sp += __shfl_xor(sp, 4); sn += __shfl_xor(sn, 4);
        const float a = ep / sp - en / sn;

        int nb = deg - base;
        if (nb > 8) nb = 8;
        for (int jj = 0; jj < nb; ++jj) {
            const int   dd = __shfl(dj, jj * 8);
            const float av = __shfl(a,  jj * 8 + myhead);
            const ushort4 vv = V4[dd * 64 + lane];
            acc.x = fmaf(bf16f((short)vv.x), av, acc.x);
            acc.y = fmaf(bf16f((short)vv.y), av, acc.y);
            acc.z = fmaf(bf16f((short)vv.z), av, acc.z);
            acc.w = fmaf(bf16f((short)vv.w), av, acc.w);
        }
    }
    ((float4*)out)[s * 64 + lane] = acc;   // every node written -> no memset
}

extern "C" void kernel_launch(void* const* d_in, const int* in_sizes, int n_in,
                              void* d_out, int out_size, void* d_ws, size_t ws_size,
                              hipStream_t stream) {
    const float* x   = (const float*)d_in[0];
    const float* Wq  = (const float*)d_in[1];
    const float* Wk  = (const float*)d_in[2];
    const float* Wv  = (const float*)d_in[3];
    const float* RF  = (const float*)d_in[4];
    const float* RFq = (const float*)d_in[5];
    const int* eidx  = (const int*)d_in[6];
    const int* esign = (const int*)d_in[7];
    const int* src = eidx;            // edge_index[0, :]
    const int* dst = eidx + E_EDGES;  // edge_index[1, :]
    float* out = (float*)d_out;

    // Workspace layout: Vb(bf16, in N*256-float region) | Sq | Phi | pk_pos |
    //   pk_neg | cnt_pos | cnt_neg | srcCnt | dstCnt | srcBucket | dstBucket |
    //   bf16 weights
    float* ws      = (float*)d_ws;
    unsigned short* Vb = (unsigned short*)ws;             // N*256 bf16 (uses half region)
    float* Sq      = ws + (size_t)N_NODES * HD;           // N*8
    float* Phi     = Sq + (size_t)N_NODES * H_HEADS;      // 6250*64 = 400000
    float* pk_pos  = Phi + (size_t)N_NODES * M_FEAT;      // N*8
    float* pk_neg  = pk_pos + (size_t)N_NODES * H_HEADS;  // N*8
    float* cnt_pos = pk_neg + (size_t)N_NODES * H_HEADS;  // N
    float* cnt_neg = cnt_pos + N_NODES;                   // N
    int* srcCnt    = (int*)(cnt_neg + N_NODES);           // N
    int* dstCnt    = srcCnt + N_NODES;                    // N
    int* srcBucket = dstCnt + N_NODES;                    // N*CAP
    unsigned* dstBucket = (unsigned*)(srcBucket + (size_t)N_NODES * CAP); // N*CAP
    unsigned short* WqTh = (unsigned short*)(dstBucket + (size_t)N_NODES * CAP);
    unsigned short* WqTl = WqTh + 64 * IN_DIM;            // 8192 each
    unsigned short* WkTh = WqTl + 64 * IN_DIM;
    unsigned short* WkTl = WkTh + 64 * IN_DIM;
    unsigned short* WvT  = WkTl + 64 * IN_DIM;            // 256*128

    // Zero only the bucket counters (contiguous 2*N ints).
    hipMemsetAsync(srcCnt, 0, sizeof(int) * (size_t)N_NODES * 2, stream);

    prep_kernel<<<192, 256, 0, stream>>>(Wq, Wk, Wv, RF, RFq,
                                         WqTh, WqTl, WkTh, WkTl, WvT);
    bucket_kernel<<<(E_EDGES + 255) / 256, 256, 0, stream>>>(
        src, dst, esign, srcCnt, srcBucket, dstCnt, dstBucket);
    xform_kernel<<<N_NODES / 16, 256, 0, stream>>>(
        x, WvT, WqTh, WqTl, WkTh, WkTl, Vb, Sq, Phi);
    pk_kernel<<<(N_NODES * H_HEADS + 255) / 256, 256, 0, stream>>>(
        dstCnt, dstBucket, Phi, pk_pos, pk_neg, cnt_pos, cnt_neg);
    accum_kernel<<<N_NODES / 4, 256, 0, stream>>>(
        srcCnt, srcBucket, Sq, pk_pos, pk_neg, cnt_pos, cnt_neg, Vb, out);
}

// Round 8
// 244.303 us; speedup vs baseline: 1.4949x; 1.0420x over previous
//
#include <hip/hip_runtime.h>

// Problem constants (fixed by the reference)
constexpr int N_NODES = 50000;
constexpr int E_EDGES = 400000;
constexpr int IN_DIM  = 128;
constexpr int HD      = 256;   // H*D
constexpr int H_HEADS = 8;
constexpr int D_HEAD  = 32;
constexpr int M_FEAT  = 8;
constexpr int K_NODES = N_NODES / H_HEADS;   // 6250 nodes need Phi
constexpr int CAP     = 48;    // bucket capacity; deg ~ Poisson(8), P(>=48) ~ 1e-23
constexpr int BUCKET_BLOCKS = (E_EDGES + 255) / 256;   // 1563
constexpr int XFORM_BLOCKS  = N_NODES / 16;            // 3125

typedef __attribute__((ext_vector_type(8))) short bf16x8;
typedef __attribute__((ext_vector_type(4))) float f32x4;

__device__ inline short to_bf16(float f) {
    unsigned u = __builtin_bit_cast(unsigned, f);
    u += 0x7FFFu + ((u >> 16) & 1u);   // RNE; inputs are finite
    return (short)(u >> 16);
}
__device__ inline float bf16f(short h) {
    return __builtin_bit_cast(float, (unsigned)(unsigned short)h << 16);
}

// ---------------------------------------------------------------------------
// Prep kernel (also zeroes the bucket counters -> no separate memset).
//   blocks [0,32):    Wq x RFq fold -> split-bf16 transposed WqTh/WqTl[c*128+d]
//   blocks [32,64):   Wk x RF fold  -> WkTh/WkTl
//   blocks [64,192):  WvT[n*128+d] = bf16(Wv[d][n])  (col-major B layout)
//   blocks [192,290): zero srcCnt/dstCnt (100000 ints, int4 stores)
// ---------------------------------------------------------------------------
__global__ __launch_bounds__(256) void prep_kernel(
    const float* __restrict__ Wq, const float* __restrict__ Wk,
    const float* __restrict__ Wv, const float* __restrict__ RF,
    const float* __restrict__ RFq,
    unsigned short* __restrict__ WqTh, unsigned short* __restrict__ WqTl,
    unsigned short* __restrict__ WkTh, unsigned short* __restrict__ WkTl,
    unsigned short* __restrict__ WvT, int* __restrict__ cnts)
{
    const int b = blockIdx.x;
    const int t = threadIdx.x;
    if (b < 64) {
        const bool isQ = (b < 32);
        const int idx = (isQ ? b : b - 32) * 256 + t;   // 0..8191
        const int d = idx >> 6;
        const int c = idx & 63;
        const int hj = c >> 3, m = c & 7;
        const float* W = isQ ? Wq : Wk;
        const float* R = isQ ? RFq : RF;
        float acc = 0.f;
        #pragma unroll
        for (int dd = 0; dd < D_HEAD; ++dd)
            acc = fmaf(W[d * HD + hj * D_HEAD + dd], R[dd * M_FEAT + m], acc);
        const short h = to_bf16(acc);
        const short l = to_bf16(acc - bf16f(h));
        (isQ ? WqTh : WkTh)[c * IN_DIM + d] = (unsigned short)h;
        (isQ ? WqTl : WkTl)[c * IN_DIM + d] = (unsigned short)l;
    } else if (b < 192) {
        const int idx = (b - 64) * 256 + t;             // 0..32767
        const int n = idx >> 7;
        const int d = idx & 127;
        WvT[idx] = (unsigned short)to_bf16(Wv[d * HD + n]);
    } else {
        const int idx = (b - 192) * 256 + t;            // int4 index
        if (idx < (2 * N_NODES) / 4)
            ((int4*)cnts)[idx] = make_int4(0, 0, 0, 0);
    }
}

// ---------------------------------------------------------------------------
// Fused main kernel: heterogeneous grid.
//   blocks [0,1563):     bucket edges by src (dst) and by dst (src|sign)
//   blocks [1563,4688):  xform — 16-row tile, 4 waves split columns
// Fusing lets bucket's atomic latency hide under xform's L2-load stalls
// (both were latency-bound with all pipes <15% busy when run serially).
// __launch_bounds__(256,4): 128-VGPR budget so B-frags can be hoisted.
// Fragment maps (verified round 4): A[m=lane&15][k=quad*8+j],
// B[k=quad*8+j][n=lane&15] (col-major, k-contig), C col=lane&15 row=quad*4+r.
// ---------------------------------------------------------------------------
__global__ __launch_bounds__(256, 4) void main_kernel(
    const int* __restrict__ src, const int* __restrict__ dst,
    const int* __restrict__ sign,
    int* __restrict__ srcCnt, int* __restrict__ srcBucket,
    int* __restrict__ dstCnt, unsigned* __restrict__ dstBucket,
    const float* __restrict__ x, const unsigned short* __restrict__ WvT,
    const unsigned short* __restrict__ WqTh, const unsigned short* __restrict__ WqTl,
    const unsigned short* __restrict__ WkTh, const unsigned short* __restrict__ WkTl,
    unsigned short* __restrict__ Vb, float* __restrict__ Sq, float* __restrict__ Phi)
{
    if (blockIdx.x < BUCKET_BLOCKS) {
        const int e = blockIdx.x * 256 + threadIdx.x;
        if (e >= E_EDGES) return;
        const int s = src[e];
        const int d = dst[e];
        const unsigned pos = (sign[e] == 1) ? 0x80000000u : 0u;
        const int ss = atomicAdd(&srcCnt[s], 1);
        if (ss < CAP) srcBucket[s * CAP + ss] = d;
        const int ds = atomicAdd(&dstCnt[d], 1);
        if (ds < CAP) dstBucket[d * CAP + ds] = (unsigned)s | pos;
        return;
    }

    const int r0   = (blockIdx.x - BUCKET_BLOCKS) * 16;
    const int w    = threadIdx.x >> 6;   // wave id 0..3 = column group
    const int lane = threadIdx.x & 63;
    const int m    = lane & 15;
    const int quad = lane >> 4;

    // A fragments, split hi/lo (K=128 -> 4 k-steps).
    bf16x8 Ah[4], Al[4];
    const float* xrow = x + (size_t)(r0 + m) * IN_DIM;
    #pragma unroll
    for (int t = 0; t < 4; ++t) {
        const float4 a = *(const float4*)(xrow + t * 32 + quad * 8);
        const float4 b = *(const float4*)(xrow + t * 32 + quad * 8 + 4);
        float vals[8] = {a.x, a.y, a.z, a.w, b.x, b.y, b.z, b.w};
        bf16x8 fh, fl;
        #pragma unroll
        for (int e = 0; e < 8; ++e) {
            const short hh = to_bf16(vals[e]);
            fh[e] = hh;
            fl[e] = to_bf16(vals[e] - bf16f(hh));
        }
        Ah[t] = fh; Al[t] = fl;
    }

    // ---- V = x @ Wv: this wave's 4 col-tiles, B-frags hoisted in pairs ----
    const unsigned short* bp = WvT + (size_t)m * IN_DIM + quad * 8;
    #pragma unroll
    for (int ii = 0; ii < 2; ++ii) {
        bf16x8 Bv[8];
        #pragma unroll
        for (int i = 0; i < 2; ++i) {
            const unsigned short* bc =
                bp + (size_t)(w * 4 + ii * 2 + i) * 16 * IN_DIM;
            #pragma unroll
            for (int t = 0; t < 4; ++t)
                Bv[i * 4 + t] = *(const bf16x8*)(bc + t * 32);
        }
        #pragma unroll
        for (int i = 0; i < 2; ++i) {
            const int ct = w * 4 + ii * 2 + i;
            f32x4 acc = {0.f, 0.f, 0.f, 0.f};
            #pragma unroll
            for (int t = 0; t < 4; ++t)
                acc = __builtin_amdgcn_mfma_f32_16x16x32_bf16(Ah[t], Bv[i * 4 + t], acc, 0, 0, 0);
            #pragma unroll
            for (int r = 0; r < 4; ++r)
                Vb[(size_t)(r0 + quad * 4 + r) * HD + ct * 16 + m] =
                    (unsigned short)to_bf16(acc[r]);
        }
    }

    // ---- q-path: col-tile w (pair precision), then Sq ----
    {
        const int c = w * 16 + m;   // my C column
        const unsigned short* bh = WqTh + (size_t)c * IN_DIM + quad * 8;
        const unsigned short* bl = WqTl + (size_t)c * IN_DIM + quad * 8;
        bf16x8 Bh[4], Bl[4];
        #pragma unroll
        for (int t = 0; t < 4; ++t) {
            Bh[t] = *(const bf16x8*)(bh + t * 32);
            Bl[t] = *(const bf16x8*)(bl + t * 32);
        }
        f32x4 acc1 = {0.f, 0.f, 0.f, 0.f};
        f32x4 acc2 = {0.f, 0.f, 0.f, 0.f};
        #pragma unroll
        for (int t = 0; t < 4; ++t) {
            acc1 = __builtin_amdgcn_mfma_f32_16x16x32_bf16(Ah[t], Bh[t], acc1, 0, 0, 0);
            acc2 = __builtin_amdgcn_mfma_f32_16x16x32_bf16(Al[t], Bh[t], acc2, 0, 0, 0);
        }
        #pragma unroll
        for (int t = 0; t < 4; ++t)
            acc1 = __builtin_amdgcn_mfma_f32_16x16x32_bf16(Ah[t], Bl[t], acc1, 0, 0, 0);
        #pragma unroll
        for (int r = 0; r < 4; ++r) {
            const float pv = acc1[r] + acc2[r];
            float tv = __cosf(pv) + __sinf(pv);
            tv += __shfl_xor(tv, 1);
            tv += __shfl_xor(tv, 2);
            tv += __shfl_xor(tv, 4);
            if ((lane & 7) == 0) {
                const int h = w * 2 + (m >> 3);
                Sq[(r0 + quad * 4 + r) * H_HEADS + h] = tv;
            }
        }
    }

    // ---- k-path: col-tile w, Phi for rows < 6250 (wave-uniform skip) ----
    if (r0 < K_NODES) {
        const int c = w * 16 + m;
        const unsigned short* bh = WkTh + (size_t)c * IN_DIM + quad * 8;
        const unsigned short* bl = WkTl + (size_t)c * IN_DIM + quad * 8;
        bf16x8 Bh[4], Bl[4];
        #pragma unroll
        for (int t = 0; t < 4; ++t) {
            Bh[t] = *(const bf16x8*)(bh + t * 32);
            Bl[t] = *(const bf16x8*)(bl + t * 32);
        }
        f32x4 acc1 = {0.f, 0.f, 0.f, 0.f};
        f32x4 acc2 = {0.f, 0.f, 0.f, 0.f};
        #pragma unroll
        for (int t = 0; t < 4; ++t) {
            acc1 = __builtin_amdgcn_mfma_f32_16x16x32_bf16(Ah[t], Bh[t], acc1, 0, 0, 0);
            acc2 = __builtin_amdgcn_mfma_f32_16x16x32_bf16(Al[t], Bh[t], acc2, 0, 0, 0);
        }
        #pragma unroll
        for (int t = 0; t < 4; ++t)
            acc1 = __builtin_amdgcn_mfma_f32_16x16x32_bf16(Ah[t], Bl[t], acc1, 0, 0, 0);
        #pragma unroll
        for (int r = 0; r < 4; ++r) {
            const int row = r0 + quad * 4 + r;
            if (row < K_NODES) {
                const float pv = acc1[r] + acc2[r];
                Phi[(size_t)row * 64 + c] = __cosf(pv) + __sinf(pv);
            }
        }
    }
}

// ---------------------------------------------------------------------------
// Gather-build pk_pos/pk_neg [N,8] and cnt_pos/cnt_neg [N]; thread per (dst,h).
// Phi flat index for flat row s = n*8+j, feature m:  s*8+m == n*64 + j*8 + m.
// ---------------------------------------------------------------------------
__global__ __launch_bounds__(256) void pk_kernel(
    const int* __restrict__ dstCnt, const unsigned* __restrict__ dstBucket,
    const float* __restrict__ Phi,
    float* __restrict__ pk_pos, float* __restrict__ pk_neg,
    float* __restrict__ cnt_pos, float* __restrict__ cnt_neg)
{
    const int t = blockIdx.x * 256 + threadIdx.x;
    if (t >= N_NODES * H_HEADS) return;
    const int d = t >> 3;
    const int h = t & 7;
    int deg = dstCnt[d];
    if (deg > CAP) deg = CAP;

    float accp = 0.f, accn = 0.f;
    int cp = 0, cn = 0;
    for (int i = 0; i < deg; ++i) {
        const unsigned entry = dstBucket[d * CAP + i];
        const int s = (int)(entry & 0x7FFFFFFFu);
        const float phi = Phi[s * H_HEADS + h];
        if (entry & 0x80000000u) { accp += phi; ++cp; }
        else                     { accn += phi; ++cn; }
    }
    pk_pos[t] = accp;
    pk_neg[t] = accn;
    if (h == 0) {
        cnt_pos[d] = (float)cp;
        cnt_neg[d] = (float)cn;
    }
}

// ---------------------------------------------------------------------------
// Gather-accumulate. One wave per src node. V gathered as bf16 (ushort4 = 8 B
// per lane, 512 B per row per wave, coalesced), fp32 accumulate.
// ---------------------------------------------------------------------------
__global__ __launch_bounds__(256) void accum_kernel(
    const int* __restrict__ srcCnt, const int* __restrict__ srcBucket,
    const float* __restrict__ Sq,
    const float* __restrict__ pk_pos, const float* __restrict__ pk_neg,
    const float* __restrict__ cnt_pos, const float* __restrict__ cnt_neg,
    const unsigned short* __restrict__ Vb, float* __restrict__ out)
{
    const int s = blockIdx.x * 4 + (threadIdx.x >> 6);
    const int lane = threadIdx.x & 63;
    const int j = lane >> 3;       // edge slot within batch
    const int h = lane & 7;        // head for attn compute
    const int myhead = lane >> 3;  // head of my output columns (c=4*lane)

    int deg = srcCnt[s];
    if (deg > CAP) deg = CAP;
    const float sq = Sq[s * H_HEADS + h];

    float4 acc = make_float4(0.f, 0.f, 0.f, 0.f);
    const ushort4* __restrict__ V4 = (const ushort4*)Vb;   // 64 ushort4 per row

    for (int base = 0; base < deg; base += 8) {
        const int idx = base + j;
        const int dj = (idx < deg) ? srcBucket[s * CAP + idx] : 0;

        const float dp = fmaxf(cnt_pos[dj], 1.0f);
        const float dn = fmaxf(cnt_neg[dj], 1.0f);
        float np = sq * pk_pos[dj * H_HEADS + h] / dp;
        float nn = sq * pk_neg[dj * H_HEADS + h] / dn;

        float mp = np, mn = nn;
        mp = fmaxf(mp, __shfl_xor(mp, 1)); mn = fmaxf(mn, __shfl_xor(mn, 1));
        mp = fmaxf(mp, __shfl_xor(mp, 2)); mn = fmaxf(mn, __shfl_xor(mn, 2));
        mp = fmaxf(mp, __shfl_xor(mp, 4)); mn = fmaxf(mn, __shfl_xor(mn, 4));
        float ep = __expf(np - mp), en = __expf(nn - mn);
        float sp = ep, sn = en;
        sp += __shfl_xor(sp, 1); sn += __shfl_xor(sn, 1);
        sp += __shfl_xor(sp, 2); sn += __shfl_xor(sn, 2);
        sp += __shfl_xor(sp, 4); sn += __shfl_xor(sn, 4);
        const float a = ep / sp - en / sn;

        int nb = deg - base;
        if (nb > 8) nb = 8;
        for (int jj = 0; jj < nb; ++jj) {
            const int   dd = __shfl(dj, jj * 8);
            const float av = __shfl(a,  jj * 8 + myhead);
            const ushort4 vv = V4[dd * 64 + lane];
            acc.x = fmaf(bf16f((short)vv.x), av, acc.x);
            acc.y = fmaf(bf16f((short)vv.y), av, acc.y);
            acc.z = fmaf(bf16f((short)vv.z), av, acc.z);
            acc.w = fmaf(bf16f((short)vv.w), av, acc.w);
        }
    }
    ((float4*)out)[s * 64 + lane] = acc;   // every node written -> no memset
}

extern "C" void kernel_launch(void* const* d_in, const int* in_sizes, int n_in,
                              void* d_out, int out_size, void* d_ws, size_t ws_size,
                              hipStream_t stream) {
    const float* x   = (const float*)d_in[0];
    const float* Wq  = (const float*)d_in[1];
    const float* Wk  = (const float*)d_in[2];
    const float* Wv  = (const float*)d_in[3];
    const float* RF  = (const float*)d_in[4];
    const float* RFq = (const float*)d_in[5];
    const int* eidx  = (const int*)d_in[6];
    const int* esign = (const int*)d_in[7];
    const int* src = eidx;            // edge_index[0, :]
    const int* dst = eidx + E_EDGES;  // edge_index[1, :]
    float* out = (float*)d_out;

    // Workspace layout: Vb(bf16, in N*256-float region) | Sq | Phi | pk_pos |
    //   pk_neg | cnt_pos | cnt_neg | srcCnt | dstCnt | srcBucket | dstBucket |
    //   bf16 weights
    float* ws      = (float*)d_ws;
    unsigned short* Vb = (unsigned short*)ws;             // N*256 bf16 (half region)
    float* Sq      = ws + (size_t)N_NODES * HD;           // N*8
    float* Phi     = Sq + (size_t)N_NODES * H_HEADS;      // 6250*64 = 400000
    float* pk_pos  = Phi + (size_t)N_NODES * M_FEAT;      // N*8
    float* pk_neg  = pk_pos + (size_t)N_NODES * H_HEADS;  // N*8
    float* cnt_pos = pk_neg + (size_t)N_NODES * H_HEADS;  // N
    float* cnt_neg = cnt_pos + N_NODES;                   // N
    int* srcCnt    = (int*)(cnt_neg + N_NODES);           // N
    int* dstCnt    = srcCnt + N_NODES;                    // N
    int* srcBucket = dstCnt + N_NODES;                    // N*CAP
    unsigned* dstBucket = (unsigned*)(srcBucket + (size_t)N_NODES * CAP); // N*CAP
    unsigned short* WqTh = (unsigned short*)(dstBucket + (size_t)N_NODES * CAP);
    unsigned short* WqTl = WqTh + 64 * IN_DIM;            // 8192 each
    unsigned short* WkTh = WqTl + 64 * IN_DIM;
    unsigned short* WkTl = WkTh + 64 * IN_DIM;
    unsigned short* WvT  = WkTl + 64 * IN_DIM;            // 256*128

    prep_kernel<<<290, 256, 0, stream>>>(Wq, Wk, Wv, RF, RFq,
                                         WqTh, WqTl, WkTh, WkTl, WvT, srcCnt);
    main_kernel<<<BUCKET_BLOCKS + XFORM_BLOCKS, 256, 0, stream>>>(
        src, dst, esign, srcCnt, srcBucket, dstCnt, dstBucket,
        x, WvT, WqTh, WqTl, WkTh, WkTl, Vb, Sq, Phi);
    pk_kernel<<<(N_NODES * H_HEADS + 255) / 256, 256, 0, stream>>>(
        dstCnt, dstBucket, Phi, pk_pos, pk_neg, cnt_pos, cnt_neg);
    accum_kernel<<<N_NODES / 4, 256, 0, stream>>>(
        srcCnt, srcBucket, Sq, pk_pos, pk_neg, cnt_pos, cnt_neg, Vb, out);
}